// Round 10
// baseline (24.700 us; speedup 1.0000x reference)
//
#include <hip/hip_runtime.h>
#include <hip/hip_fp16.h>

// bg: (1,4,32,32,32,16) f32 ; gm: (1,1,128,128,128) f32 ; out: (1,4,128,128,128) f32
//
// v10: wave-private k-column software pipeline, NO barriers.
// 2048 waves (512 blocks x 4). Wave = 4(i) x 4(j) column, 4 chunks of 16 k.
// Private LDS: 54 nodes (3x*3y*6z) * 36 dw (144B) = 7776 B, single buffer.
// Per chunk: pack+ds_write(c) [vmcnt-counted wait on loads issued last chunk]
// -> issue chunk c+1 global loads (hide under interp) -> interp(c).
// Interp body identical to proven v7/v9 (fp16 xy-accum, b64-pair reads).

#define S_ (31.0f / 127.0f)
#define CH_STRIDE 524288
#define TOTAL 2097152

#define NODE_DW 36                 // 32 data dwords + 4 pad (bank spread)
#define WAVE_DW (54 * NODE_DW)     // 1944 dw = 7776 B per wave
#define XS (18 * NODE_DW)
#define YS (6 * NODE_DW)

#define PK(x, y) __builtin_bit_cast(float, __floats2half2_rn((x), (y)))
#define H2(f) __builtin_bit_cast(__half2, f)

__global__ __launch_bounds__(256, 2) void bgrid_slice_v10(
    const float* __restrict__ bg,
    const float* __restrict__ gm,
    float* __restrict__ out)
{
    __shared__ __align__(16) float lds_all[4 * WAVE_DW];   // 31104 B

    const int tid = threadIdx.x;
    const int wave = tid >> 6, lane = tid & 63;
    // XCD-chunked swizzle over 512 blocks (512 % 8 == 0, bijective).
    const int b = blockIdx.x;
    const int bs = ((b & 7) << 6) + (b >> 3);
    const int gw = (bs << 2) + wave;              // global wave id 0..2047
    const int wk = gw & 1;                        // k half (64 k)
    const int wj = (gw >> 1) & 31;                // j tile (4 j)
    const int wi = gw >> 6;                       // i tile (4 i)

    const int i0 = wi * 4, j0 = wj * 4, K0 = wk * 64;
    const int x_base = (int)((float)i0 * S_);
    const int y_base = (int)((float)j0 * S_);
    float* lds = lds_all + wave * WAVE_DW;

    const int kq = lane & 3, lj = (lane >> 2) & 3, li = lane >> 4;
    const int i = i0 + li, j = j0 + lj;

    // ---- staging item constants (q = lane + 64r over 216 items) ----
    // rounds 0..2 fully active; round 3 active for lane < 24.
    int sxy[4], sdz[4], sdst[4];
    #pragma unroll
    for (int r = 0; r < 4; ++r) {
        const int q = lane + (r << 6);
        const int qq = (q < 216) ? q : 0;
        const int seg = qq & 3;
        const int node = qq >> 2;                 // 0..53
        const int a = node / 18;
        const int rem = node - a * 18;
        const int bb = rem / 6;
        const int cz = rem - bb * 6;
        const int gx = min(x_base + a, 31);
        const int gy = min(y_base + bb, 31);
        sxy[r] = (((gx * 32 + gy) * 32) << 4) + (seg << 2);   // + gz*16 later
        sdz[r] = cz;
        sdst[r] = node * NODE_DW + (seg << 3);
    }
    const bool act3 = (lane < 24);

    // ---- interp constants (fixed for the whole column) ----
    const float xf = fminf((float)i * S_, 31.0f);
    const float yf = fminf((float)j * S_, 31.0f);
    const int x0g = (int)xf; const float fx = xf - (float)x0g;
    const int y0g = (int)yf; const float fy = yf - (float)y0g;
    const int AX0 = (x0g - x_base) * XS;
    const int AX1 = (min(x0g + 1, 31) - x_base) * XS;
    const int BY0 = (y0g - y_base) * YS;
    const int BY1 = (min(y0g + 1, 31) - y_base) * YS;

    const float wx1 = fx, wx0 = 1.0f - fx;
    const float wy1 = fy, wy0 = 1.0f - fy;
    const __half2 W00 = __float2half2_rn(wx0 * wy0);
    const __half2 W01 = __float2half2_rn(wx0 * wy1);
    const __half2 W10 = __float2half2_rn(wx1 * wy0);
    const __half2 W11 = __float2half2_rn(wx1 * wy1);

    const int colidx = (i << 14) | (j << 7);

    // ---- prologue: issue loads for chunk 0 ----
    float4 L[4][4];
    float4 g;
    {
        const int zb0 = (int)((float)K0 * S_);
        #pragma unroll
        for (int r = 0; r < 4; ++r) {
            if (r < 3 || act3) {
                const int gz = min(zb0 + sdz[r], 31);
                const int gb = sxy[r] + (gz << 4);
                L[r][0] = *(const float4*)&bg[gb];
                L[r][1] = *(const float4*)&bg[gb + CH_STRIDE];
                L[r][2] = *(const float4*)&bg[gb + 2 * CH_STRIDE];
                L[r][3] = *(const float4*)&bg[gb + 3 * CH_STRIDE];
            }
        }
        g = *(const float4*)&gm[colidx + K0 + (kq << 2)];
    }

    #pragma unroll
    for (int c = 0; c < 4; ++c) {
        const int k0 = K0 + c * 16;
        const int zb = (int)((float)k0 * S_);

        // ---- pack + ds_write chunk c (first use of L -> counted vmcnt wait) ----
        #pragma unroll
        for (int r = 0; r < 4; ++r) {
            if (r < 3 || act3) {
                float4 V0, V1;
                V0.x = PK(L[r][0].x, L[r][1].x); V0.y = PK(L[r][2].x, L[r][3].x);
                V0.z = PK(L[r][0].y, L[r][1].y); V0.w = PK(L[r][2].y, L[r][3].y);
                V1.x = PK(L[r][0].z, L[r][1].z); V1.y = PK(L[r][2].z, L[r][3].z);
                V1.z = PK(L[r][0].w, L[r][1].w); V1.w = PK(L[r][2].w, L[r][3].w);
                *(float4*)&lds[sdst[r]] = V0;
                *(float4*)&lds[sdst[r] + 4] = V1;
            }
        }

        // ---- issue chunk c+1 loads (stay in flight across interp) ----
        float4 Ln[4][4]; float4 gn;
        if (c < 3) {
            const int zbn = (int)((float)(k0 + 16) * S_);
            #pragma unroll
            for (int r = 0; r < 4; ++r) {
                if (r < 3 || act3) {
                    const int gz = min(zbn + sdz[r], 31);
                    const int gb = sxy[r] + (gz << 4);
                    Ln[r][0] = *(const float4*)&bg[gb];
                    Ln[r][1] = *(const float4*)&bg[gb + CH_STRIDE];
                    Ln[r][2] = *(const float4*)&bg[gb + 2 * CH_STRIDE];
                    Ln[r][3] = *(const float4*)&bg[gb + 3 * CH_STRIDE];
                }
            }
            gn = *(const float4*)&gm[colidx + k0 + 16 + (kq << 2)];
        }

        // ---- interp chunk c: 4 voxels ----
        const int kk = k0 + (kq << 2);
        const int idx = colidx + kk;
        float o0[4], o1[4], o2[4], o3[4];

        #pragma unroll
        for (int v = 0; v < 4; ++v) {
            const float gv = (v == 0) ? g.x : (v == 1) ? g.y : (v == 2) ? g.z : g.w;
            float t = fminf(fmaxf(gv * 15.0f, 0.0f), 15.0f);
            const int t0 = min((int)t, 14);
            const float ft = t - (float)t0;
            const __half2 ft2 = __float2half2_rn(ft);

            const float zf = fminf((float)(kk + v) * S_, 31.0f);
            const int z0g = (int)zf;
            const float fz = zf - (float)z0g;
            const int zi0 = z0g - zb;
            const int zi1 = min(z0g + 1, 31) - zb;
            const __half2 fz2 = __float2half2_rn(fz);

            const int CZ0 = zi0 * NODE_DW + (t0 << 1);
            const int CZ1 = zi1 * NODE_DW + (t0 << 1);

            const float2 a00lo = *(const float2*)&lds[AX0 + BY0 + CZ0];
            const float2 a00hi = *(const float2*)&lds[AX0 + BY0 + CZ0 + 2];
            const float2 a01lo = *(const float2*)&lds[AX0 + BY1 + CZ0];
            const float2 a01hi = *(const float2*)&lds[AX0 + BY1 + CZ0 + 2];
            const float2 a10lo = *(const float2*)&lds[AX1 + BY0 + CZ0];
            const float2 a10hi = *(const float2*)&lds[AX1 + BY0 + CZ0 + 2];
            const float2 a11lo = *(const float2*)&lds[AX1 + BY1 + CZ0];
            const float2 a11hi = *(const float2*)&lds[AX1 + BY1 + CZ0 + 2];
            const float2 b00lo = *(const float2*)&lds[AX0 + BY0 + CZ1];
            const float2 b00hi = *(const float2*)&lds[AX0 + BY0 + CZ1 + 2];
            const float2 b01lo = *(const float2*)&lds[AX0 + BY1 + CZ1];
            const float2 b01hi = *(const float2*)&lds[AX0 + BY1 + CZ1 + 2];
            const float2 b10lo = *(const float2*)&lds[AX1 + BY0 + CZ1];
            const float2 b10hi = *(const float2*)&lds[AX1 + BY0 + CZ1 + 2];
            const float2 b11lo = *(const float2*)&lds[AX1 + BY1 + CZ1];
            const float2 b11hi = *(const float2*)&lds[AX1 + BY1 + CZ1 + 2];

            __half2 Plo01 = __hmul2(W00, H2(a00lo.x));
            __half2 Plo23 = __hmul2(W00, H2(a00lo.y));
            __half2 Phi01 = __hmul2(W00, H2(a00hi.x));
            __half2 Phi23 = __hmul2(W00, H2(a00hi.y));
            Plo01 = __hfma2(W01, H2(a01lo.x), Plo01);
            Plo23 = __hfma2(W01, H2(a01lo.y), Plo23);
            Phi01 = __hfma2(W01, H2(a01hi.x), Phi01);
            Phi23 = __hfma2(W01, H2(a01hi.y), Phi23);
            Plo01 = __hfma2(W10, H2(a10lo.x), Plo01);
            Plo23 = __hfma2(W10, H2(a10lo.y), Plo23);
            Phi01 = __hfma2(W10, H2(a10hi.x), Phi01);
            Phi23 = __hfma2(W10, H2(a10hi.y), Phi23);
            Plo01 = __hfma2(W11, H2(a11lo.x), Plo01);
            Plo23 = __hfma2(W11, H2(a11lo.y), Plo23);
            Phi01 = __hfma2(W11, H2(a11hi.x), Phi01);
            Phi23 = __hfma2(W11, H2(a11hi.y), Phi23);

            __half2 Qlo01 = __hmul2(W00, H2(b00lo.x));
            __half2 Qlo23 = __hmul2(W00, H2(b00lo.y));
            __half2 Qhi01 = __hmul2(W00, H2(b00hi.x));
            __half2 Qhi23 = __hmul2(W00, H2(b00hi.y));
            Qlo01 = __hfma2(W01, H2(b01lo.x), Qlo01);
            Qlo23 = __hfma2(W01, H2(b01lo.y), Qlo23);
            Qhi01 = __hfma2(W01, H2(b01hi.x), Qhi01);
            Qhi23 = __hfma2(W01, H2(b01hi.y), Qhi23);
            Qlo01 = __hfma2(W10, H2(b10lo.x), Qlo01);
            Qlo23 = __hfma2(W10, H2(b10lo.y), Qlo23);
            Qhi01 = __hfma2(W10, H2(b10hi.x), Qhi01);
            Qhi23 = __hfma2(W10, H2(b10hi.y), Qhi23);
            Qlo01 = __hfma2(W11, H2(b11lo.x), Qlo01);
            Qlo23 = __hfma2(W11, H2(b11lo.y), Qlo23);
            Qhi01 = __hfma2(W11, H2(b11hi.x), Qhi01);
            Qhi23 = __hfma2(W11, H2(b11hi.y), Qhi23);

            const __half2 Rlo01 = __hfma2(fz2, __hsub2(Qlo01, Plo01), Plo01);
            const __half2 Rlo23 = __hfma2(fz2, __hsub2(Qlo23, Plo23), Plo23);
            const __half2 Rhi01 = __hfma2(fz2, __hsub2(Qhi01, Phi01), Phi01);
            const __half2 Rhi23 = __hfma2(fz2, __hsub2(Qhi23, Phi23), Phi23);

            const __half2 r01 = __hfma2(ft2, __hsub2(Rhi01, Rlo01), Rlo01);
            const __half2 r23 = __hfma2(ft2, __hsub2(Rhi23, Rlo23), Rlo23);

            o0[v] = __low2float(r01);
            o1[v] = __high2float(r01);
            o2[v] = __low2float(r23);
            o3[v] = __high2float(r23);
        }

        float4 st;
        st.x = o0[0]; st.y = o0[1]; st.z = o0[2]; st.w = o0[3];
        *(float4*)&out[idx] = st;
        st.x = o1[0]; st.y = o1[1]; st.z = o1[2]; st.w = o1[3];
        *(float4*)&out[idx + TOTAL] = st;
        st.x = o2[0]; st.y = o2[1]; st.z = o2[2]; st.w = o2[3];
        *(float4*)&out[idx + 2 * TOTAL] = st;
        st.x = o3[0]; st.y = o3[1]; st.z = o3[2]; st.w = o3[3];
        *(float4*)&out[idx + 3 * TOTAL] = st;

        // rotate pipeline registers
        if (c < 3) {
            #pragma unroll
            for (int r = 0; r < 4; ++r) {
                #pragma unroll
                for (int ch = 0; ch < 4; ++ch) L[r][ch] = Ln[r][ch];
            }
            g = gn;
        }
    }
}

extern "C" void kernel_launch(void* const* d_in, const int* in_sizes, int n_in,
                              void* d_out, int out_size, void* d_ws, size_t ws_size,
                              hipStream_t stream) {
    const float* bg = (const float*)d_in[0];
    const float* gm = (const float*)d_in[1];
    float* out = (float*)d_out;

    dim3 grid(512);    // 2048 waves = 32(i) * 32(j) * 2(k)
    dim3 block(256);
    bgrid_slice_v10<<<grid, block, 0, stream>>>(bg, gm, out);
}

// Round 12
// 18.850 us; speedup vs baseline: 1.3104x; 1.3104x over previous
//
#include <hip/hip_runtime.h>
#include <hip/hip_fp16.h>

// bg: (1,4,32,32,32,16) f32 ; gm: (1,1,128,128,128) f32 ; out: (1,4,128,128,128) f32
//
// v11b = proven v4 structure (8x8x16 tile / 256 thr / dup-slot fp16 LDS,
// 8 x ds_read_b128 per voxel) with cheap staging, XCD swizzle, nt stores.
// LDS per node: 16 slots of 16B; slot s = {t=s: pk(c0c1),pk(c2c3) |
// t=s+1: pk(c0c1),pk(c2c3)}; slot 15 never read (t0<=14). Node stride 68 dw.

#define S_ (31.0f / 127.0f)
#define CH_STRIDE 524288
#define TOTAL 2097152

#define NX 4
#define NY 4
#define NZ 6
#define NNODES (NX * NY * NZ)      // 96
#define NODE_DW 68
#define LDS_DW (NNODES * NODE_DW)  // 6528 dw = 26112 B

#define PK(x, y) __builtin_bit_cast(float, __floats2half2_rn((x), (y)))
#define H2(f) __builtin_bit_cast(__half2, f)

typedef float vf4 __attribute__((ext_vector_type(4)));

__device__ __forceinline__ void nt_store4(float* p, float a, float b, float c, float d) {
    vf4 v; v.x = a; v.y = b; v.z = c; v.w = d;
    __builtin_nontemporal_store(v, (vf4*)p);
}

__global__ __launch_bounds__(256, 5) void bgrid_slice_v11(
    const float* __restrict__ bg,
    const float* __restrict__ gm,
    float* __restrict__ out)
{
    __shared__ __align__(16) float lds[LDS_DW];

    const int tid = threadIdx.x;
    // XCD-chunked swizzle: 2048 blocks, 8 XCDs -> 256 contiguous tiles each.
    const int b = blockIdx.x;
    const int tile = ((b & 7) << 8) + (b >> 3);
    const int bk = tile & 7;
    const int bj = (tile >> 3) & 15;
    const int bi = tile >> 7;

    const int i0 = bi * 8, j0 = bj * 8, k0 = bk * 16;
    const int x_base = (int)((float)i0 * S_);
    const int y_base = (int)((float)j0 * S_);
    const int z_base = (int)((float)k0 * S_);

    // ---- per-thread voxel ids; issue gm load before staging ----
    const int kq = tid & 3;
    const int lj = (tid >> 2) & 7;
    const int li = tid >> 5;
    const int i = i0 + li, j = j0 + lj;
    const int kk = k0 + (kq << 2);
    const int idx = (i << 14) | (j << 7) | kk;
    const float4 g4 = *(const float4*)&gm[idx];

    // ---- stage: 96 nodes * 4 segments = 384 items ----
    #pragma unroll
    for (int it = 0; it < 2; ++it) {
        const int q = tid + (it << 8);
        if (q < 384) {
            const int s4 = q & 3;            // t segment: t = 4*s4 .. 4*s4+3
            const int node = q >> 2;         // 0..95
            const int a = node / 24;
            const int rem = node - a * 24;
            const int bb = rem / 6;
            const int cz = rem - bb * 6;
            const int gx = min(x_base + a, 31);
            const int gy = min(y_base + bb, 31);
            const int gz = min(z_base + cz, 31);
            const int gbase = (((gx * 32 + gy) * 32 + gz) << 4) + (s4 << 2);

            const float4 L0 = *(const float4*)&bg[gbase];
            const float4 L1 = *(const float4*)&bg[gbase + CH_STRIDE];
            const float4 L2 = *(const float4*)&bg[gbase + 2 * CH_STRIDE];
            const float4 L3 = *(const float4*)&bg[gbase + 3 * CH_STRIDE];

            float2 p0, p1, p2, p3;           // lo2(t) for t = 4*s4+0..3
            p0.x = PK(L0.x, L1.x); p0.y = PK(L2.x, L3.x);
            p1.x = PK(L0.y, L1.y); p1.y = PK(L2.y, L3.y);
            p2.x = PK(L0.z, L1.z); p2.y = PK(L2.z, L3.z);
            p3.x = PK(L0.w, L1.w); p3.y = PK(L2.w, L3.w);

            const int s0 = node * NODE_DW + (s4 << 4);   // dw of slot 4*s4
            float4 w;
            w.x = p0.x; w.y = p0.y; w.z = p1.x; w.w = p1.y;
            *(float4*)&lds[s0] = w;                       // slot 4s4
            w.x = p1.x; w.y = p1.y; w.z = p2.x; w.w = p2.y;
            *(float4*)&lds[s0 + 4] = w;                   // slot 4s4+1
            w.x = p2.x; w.y = p2.y; w.z = p3.x; w.w = p3.y;
            *(float4*)&lds[s0 + 8] = w;                   // slot 4s4+2
            if (s4 < 3) *(float2*)&lds[s0 + 12] = p3;     // slot 4s4+3 lo
            if (s4 > 0) *(float2*)&lds[s0 - 2]  = p0;     // slot 4s4-1 hi
        }
    }
    __syncthreads();

    // ---- interp (verbatim v4 body) ----
    const float xf = fminf((float)i * S_, 31.0f);
    const float yf = fminf((float)j * S_, 31.0f);
    const int x0g = (int)xf; const float fx = xf - (float)x0g;
    const int y0g = (int)yf; const float fy = yf - (float)y0g;
    const int xi0 = x0g - x_base, xi1 = min(x0g + 1, 31) - x_base;
    const int yi0 = y0g - y_base, yi1 = min(y0g + 1, 31) - y_base;

    const int AX0 = xi0 * (NY * NZ * NODE_DW);
    const int AX1 = xi1 * (NY * NZ * NODE_DW);
    const int BY0 = yi0 * (NZ * NODE_DW);
    const int BY1 = yi1 * (NZ * NODE_DW);

    const float wx1 = fx, wx0 = 1.0f - fx;
    const float wy1 = fy, wy0 = 1.0f - fy;
    const __half2 W00 = __float2half2_rn(wx0 * wy0);
    const __half2 W01 = __float2half2_rn(wx0 * wy1);
    const __half2 W10 = __float2half2_rn(wx1 * wy0);
    const __half2 W11 = __float2half2_rn(wx1 * wy1);

    float o0[4], o1[4], o2[4], o3[4];

#pragma unroll
    for (int v = 0; v < 4; ++v) {
        const float g = (v == 0) ? g4.x : (v == 1) ? g4.y : (v == 2) ? g4.z : g4.w;
        float t = fminf(fmaxf(g * 15.0f, 0.0f), 15.0f);
        const int t0 = min((int)t, 14);
        const float ft = t - (float)t0;
        const __half2 ft2 = __float2half2_rn(ft);

        const float zf = fminf((float)(kk + v) * S_, 31.0f);
        const int z0g = (int)zf;
        const float fz = zf - (float)z0g;
        const int zi0 = z0g - z_base;
        const int zi1 = min(z0g + 1, 31) - z_base;
        const __half2 fz2 = __float2half2_rn(fz);

        const int CZ0 = zi0 * NODE_DW + (t0 << 2);
        const int CZ1 = zi1 * NODE_DW + (t0 << 2);

        const float4 a00 = *(const float4*)&lds[AX0 + BY0 + CZ0];
        const float4 a01 = *(const float4*)&lds[AX0 + BY1 + CZ0];
        const float4 a10 = *(const float4*)&lds[AX1 + BY0 + CZ0];
        const float4 a11 = *(const float4*)&lds[AX1 + BY1 + CZ0];
        const float4 b00 = *(const float4*)&lds[AX0 + BY0 + CZ1];
        const float4 b01 = *(const float4*)&lds[AX0 + BY1 + CZ1];
        const float4 b10 = *(const float4*)&lds[AX1 + BY0 + CZ1];
        const float4 b11 = *(const float4*)&lds[AX1 + BY1 + CZ1];

        __half2 Plo01 = __hmul2(W00, H2(a00.x));
        __half2 Plo23 = __hmul2(W00, H2(a00.y));
        __half2 Phi01 = __hmul2(W00, H2(a00.z));
        __half2 Phi23 = __hmul2(W00, H2(a00.w));
        Plo01 = __hfma2(W01, H2(a01.x), Plo01);
        Plo23 = __hfma2(W01, H2(a01.y), Plo23);
        Phi01 = __hfma2(W01, H2(a01.z), Phi01);
        Phi23 = __hfma2(W01, H2(a01.w), Phi23);
        Plo01 = __hfma2(W10, H2(a10.x), Plo01);
        Plo23 = __hfma2(W10, H2(a10.y), Plo23);
        Phi01 = __hfma2(W10, H2(a10.z), Phi01);
        Phi23 = __hfma2(W10, H2(a10.w), Phi23);
        Plo01 = __hfma2(W11, H2(a11.x), Plo01);
        Plo23 = __hfma2(W11, H2(a11.y), Plo23);
        Phi01 = __hfma2(W11, H2(a11.z), Phi01);
        Phi23 = __hfma2(W11, H2(a11.w), Phi23);

        __half2 Qlo01 = __hmul2(W00, H2(b00.x));
        __half2 Qlo23 = __hmul2(W00, H2(b00.y));
        __half2 Qhi01 = __hmul2(W00, H2(b00.z));
        __half2 Qhi23 = __hmul2(W00, H2(b00.w));
        Qlo01 = __hfma2(W01, H2(b01.x), Qlo01);
        Qlo23 = __hfma2(W01, H2(b01.y), Qlo23);
        Qhi01 = __hfma2(W01, H2(b01.z), Qhi01);
        Qhi23 = __hfma2(W01, H2(b01.w), Qhi23);
        Qlo01 = __hfma2(W10, H2(b10.x), Qlo01);
        Qlo23 = __hfma2(W10, H2(b10.y), Qlo23);
        Qhi01 = __hfma2(W10, H2(b10.z), Qhi01);
        Qhi23 = __hfma2(W10, H2(b10.w), Qhi23);
        Qlo01 = __hfma2(W11, H2(b11.x), Qlo01);
        Qlo23 = __hfma2(W11, H2(b11.y), Qlo23);
        Qhi01 = __hfma2(W11, H2(b11.z), Qhi01);
        Qhi23 = __hfma2(W11, H2(b11.w), Qhi23);

        const __half2 Rlo01 = __hfma2(fz2, __hsub2(Qlo01, Plo01), Plo01);
        const __half2 Rlo23 = __hfma2(fz2, __hsub2(Qlo23, Plo23), Plo23);
        const __half2 Rhi01 = __hfma2(fz2, __hsub2(Qhi01, Phi01), Phi01);
        const __half2 Rhi23 = __hfma2(fz2, __hsub2(Qhi23, Phi23), Phi23);

        const __half2 r01 = __hfma2(ft2, __hsub2(Rhi01, Rlo01), Rlo01);
        const __half2 r23 = __hfma2(ft2, __hsub2(Rhi23, Rlo23), Rlo23);

        o0[v] = __low2float(r01);
        o1[v] = __high2float(r01);
        o2[v] = __low2float(r23);
        o3[v] = __high2float(r23);
    }

    nt_store4(&out[idx],             o0[0], o0[1], o0[2], o0[3]);
    nt_store4(&out[idx + TOTAL],     o1[0], o1[1], o1[2], o1[3]);
    nt_store4(&out[idx + 2 * TOTAL], o2[0], o2[1], o2[2], o2[3]);
    nt_store4(&out[idx + 3 * TOTAL], o3[0], o3[1], o3[2], o3[3]);
}

extern "C" void kernel_launch(void* const* d_in, const int* in_sizes, int n_in,
                              void* d_out, int out_size, void* d_ws, size_t ws_size,
                              hipStream_t stream) {
    const float* bg = (const float*)d_in[0];
    const float* gm = (const float*)d_in[1];
    float* out = (float*)d_out;

    dim3 grid(2048);   // (128/8)*(128/8)*(128/16)
    dim3 block(256);
    bgrid_slice_v11<<<grid, block, 0, stream>>>(bg, gm, out);
}